// Round 8
// baseline (103.654 us; speedup 1.0000x reference)
//
#include <hip/hip_runtime.h>

// B=2, T=8192, C=64 retention attention, gamma=0.96875, GroupNorm(8), output (B,C,T)-flat.
// fp32 in/out. Sliding window of 17 64-wide s-chunks (gamma^1024 ~ 7.6e-15 << 2% threshold).
// R8: differential — qkv rewritten barrier-free/LDS-free (grid 1024 x 3-wave blocks,
// W^T fragments gathered direct from L2-hot global, 3 waves/SIMD); attn byte-identical
// to R7 (validated: lgkmcnt-hardened wave-private sS roundtrip, 4-wave chunk split).
// mfma_f32_16x16x32_f16 layouts (R4/R5/R7-validated):
//   A: m=lane&15, k=(lane>>4)*8+j   B: n=lane&15, k=(lane>>4)*8+j
//   C/D: col(n)=lane&15, row(m)=(lane>>4)*4+reg

constexpr int SEQ = 8192;
constexpr int CH  = 64;
constexpr float LOG2G = -0.045803690f;   // log2(0.96875)

typedef __attribute__((ext_vector_type(8))) _Float16     half8;
typedef __attribute__((ext_vector_type(4))) float        f32x4;
typedef __attribute__((ext_vector_type(4))) unsigned int u32x4;

__device__ inline unsigned short f2h(float x) {
    _Float16 h = (_Float16)x;
    return __builtin_bit_cast(unsigned short, h);
}

// ---------------------------------------------------------------------------
// Kernel 1: QKV projection, LDS-free. Grid 1024 (16-row tiles), block 192 = 3
// waves: role 0->Q, 1->K, 2->V. W^T fragments gathered straight from global
// (48 KB of W is L2-resident across all blocks); X fragments direct.
// Q,K: D = mfma(X, Wt) -> [t][c]. V: D = mfma(Wt_v, X) -> Vt[c][t] directly.
// ---------------------------------------------------------------------------
__global__ __launch_bounds__(192) void qkv_kernel(
    const float* __restrict__ Xin, const float* __restrict__ Wq,
    const float* __restrict__ Wk, const float* __restrict__ Wv,
    unsigned short* __restrict__ Qh, unsigned short* __restrict__ Kh,
    unsigned short* __restrict__ Vt)
{
    const int tid  = threadIdx.x;
    const int role = tid >> 6;                    // 0=Q, 1=K, 2=V
    const int lane = tid & 63;
    const int l15  = lane & 15, q4 = lane >> 4;
    const size_t row0 = (size_t)blockIdx.x * 16;  // 16-row tile
    const int b  = (int)(row0 >> 13);
    const int t0 = (int)(row0 & (SEQ - 1));

    // X fragments (A-layout == B-layout index-wise): X[row0+l15][q4*8+j]
    half8 xf[2];
    {
        const float* Xp = Xin + (row0 + l15) * 64;
        #pragma unroll
        for (int h = 0; h < 2; ++h) {
            const f32x4 a = *(const f32x4*)(Xp + h * 32 + q4 * 8);
            const f32x4 c = *(const f32x4*)(Xp + h * 32 + q4 * 8 + 4);
            half8 t;
            t[0] = (_Float16)a[0]; t[1] = (_Float16)a[1];
            t[2] = (_Float16)a[2]; t[3] = (_Float16)a[3];
            t[4] = (_Float16)c[0]; t[5] = (_Float16)c[1];
            t[6] = (_Float16)c[2]; t[7] = (_Float16)c[3];
            xf[h] = t;
        }
    }

    // W^T fragments for this wave's matrix: wf[ct][kh] element
    //   [(n|m)=ct*16+l15][k=kh*32+q4*8+j] = W[k*64 + c]  (coalesced 64B/quad)
    const float* W = (role == 0) ? Wq : ((role == 1) ? Wk : Wv);
    half8 wf[4][2];
    #pragma unroll
    for (int ct = 0; ct < 4; ++ct) {
        const int c = ct * 16 + l15;
        #pragma unroll
        for (int kh = 0; kh < 2; ++kh) {
            const int k0 = kh * 32 + q4 * 8;
            half8 t;
            #pragma unroll
            for (int j = 0; j < 8; ++j)
                t[j] = (_Float16)W[(k0 + j) * 64 + c];
            wf[ct][kh] = t;
        }
    }

    if (role < 2) {                               // Q / K: rows=t, cols=c
        unsigned short* O = (role == 0) ? Qh : Kh;
        #pragma unroll
        for (int ct = 0; ct < 4; ++ct) {
            f32x4 d = {0.f, 0.f, 0.f, 0.f};
            d = __builtin_amdgcn_mfma_f32_16x16x32_f16(xf[0], wf[ct][0], d, 0, 0, 0);
            d = __builtin_amdgcn_mfma_f32_16x16x32_f16(xf[1], wf[ct][1], d, 0, 0, 0);
            #pragma unroll
            for (int i = 0; i < 4; ++i)
                O[(row0 + q4 * 4 + i) * 64 + ct * 16 + l15] = f2h(d[i]);
        }
    } else {                                      // V^T: rows=c, cols=t
        #pragma unroll
        for (int mt = 0; mt < 4; ++mt) {
            f32x4 d = {0.f, 0.f, 0.f, 0.f};
            d = __builtin_amdgcn_mfma_f32_16x16x32_f16(wf[mt][0], xf[0], d, 0, 0, 0);
            d = __builtin_amdgcn_mfma_f32_16x16x32_f16(wf[mt][1], xf[1], d, 0, 0, 0);
            #pragma unroll
            for (int i = 0; i < 4; ++i)
                Vt[(size_t)(b * 64 + mt * 16 + q4 * 4 + i) * SEQ + t0 + l15] = f2h(d[i]);
        }
    }
}

// ---------------------------------------------------------------------------
// Kernel 2: one block per 16-row tile; 4 waves split the 17-chunk window.
// (byte-identical to R7 — validated)
// ---------------------------------------------------------------------------
__global__ __launch_bounds__(256, 4) void attn_kernel(
    const unsigned short* __restrict__ Qh, const unsigned short* __restrict__ Kh,
    const unsigned short* __restrict__ Vt,
    const float* __restrict__ gnw, const float* __restrict__ gnb,
    float* __restrict__ out)
{
    __shared__ unsigned int sS[4][16][44];       // per-wave S roundtrip (u32-typed)
    __shared__ float sO[4][16][68];              // per-wave fp32 partials
    __shared__ float sGW[64], sGB[64];

    const int tid  = threadIdx.x;
    const int w    = tid >> 6;
    const int lane = tid & 63;
    const int l15  = lane & 15, q4 = lane >> 4;
    const int tile = blockIdx.x;                 // 0..1023
    const int b    = tile >> 9;
    const int t0   = (tile & 511) << 4;

    if (tid < 64) { sGW[tid] = gnw[tid]; sGB[tid] = gnb[tid]; }

    const unsigned short* Qp = Qh + (size_t)(b * SEQ + t0 + l15) * 64 + q4 * 8;
    const half8 qf0 = *(const half8*)Qp;
    const half8 qf1 = *(const half8*)(Qp + 32);

    // decay: gamma^(t-s) = gbase * g0[i] * c16^st, t=t0+l15, s=s0+st*16+q4*4+i
    float g0[4];
    #pragma unroll
    for (int i = 0; i < 4; ++i)
        g0[i] = exp2f((float)(l15 - q4 * 4 - i) * LOG2G);
    const float c16 = exp2f(-16.f * LOG2G);      // gamma^-16
    const float c32 = c16 * c16;
    const float c48 = c32 * c16;

    f32x4 acc[4];
    #pragma unroll
    for (int ct = 0; ct < 4; ++ct) acc[ct] = (f32x4){0.f, 0.f, 0.f, 0.f};

    const int cs_hi = t0 >> 6;
    const int cs_lo = (cs_hi >= 16) ? cs_hi - 16 : 0;
    const unsigned short* Kbase = Kh + (size_t)b * SEQ * 64;
    const unsigned short* Vbase = Vt + (size_t)b * 64 * SEQ;

    for (int cs = cs_lo + w; cs <= cs_hi; cs += 4) {
        const int s0 = cs << 6;

        half8 kf[4][2];                          // K fragments (m = s)
        #pragma unroll
        for (int st = 0; st < 4; ++st) {
            const unsigned short* p = Kbase + (size_t)(s0 + st * 16 + l15) * 64 + q4 * 8;
            kf[st][0] = *(const half8*)p;
            kf[st][1] = *(const half8*)(p + 32);
        }
        f32x4 sv[4];                             // S^T = K . Q^T
        #pragma unroll
        for (int st = 0; st < 4; ++st) {
            f32x4 s = {0.f, 0.f, 0.f, 0.f};
            s = __builtin_amdgcn_mfma_f32_16x16x32_f16(kf[st][0], qf0, s, 0, 0, 0);
            s = __builtin_amdgcn_mfma_f32_16x16x32_f16(kf[st][1], qf1, s, 0, 0, 0);
            sv[st] = s;
        }

        half8 vf[4][2];                          // V^T fragments (n = c, k = s)
        #pragma unroll
        for (int ct = 0; ct < 4; ++ct) {
            const unsigned short* p = Vbase + (size_t)(ct * 16 + l15) * SEQ + s0 + q4 * 8;
            vf[ct][0] = *(const half8*)p;
            vf[ct][1] = *(const half8*)(p + 32);
        }

        const float gbase = exp2f((float)(t0 - s0) * LOG2G);
        const float gs[4] = {gbase, gbase * c16, gbase * c32, gbase * c48};
        if (cs < cs_hi) {                        // fully causal: no mask
            #pragma unroll
            for (int st = 0; st < 4; ++st) {
                const unsigned u0 = (unsigned)f2h(sv[st][0] * (gs[st] * g0[0]))
                                  | ((unsigned)f2h(sv[st][1] * (gs[st] * g0[1])) << 16);
                const unsigned u1 = (unsigned)f2h(sv[st][2] * (gs[st] * g0[2]))
                                  | ((unsigned)f2h(sv[st][3] * (gs[st] * g0[3])) << 16);
                sS[w][l15][st * 8 + q4 * 2]     = u0;
                sS[w][l15][st * 8 + q4 * 2 + 1] = u1;
            }
        } else {                                 // diagonal chunk: per-element mask
            const int dbase = t0 + l15 - s0;
            #pragma unroll
            for (int st = 0; st < 4; ++st) {
                float wt[4];
                #pragma unroll
                for (int i = 0; i < 4; ++i) {
                    const int srel = st * 16 + q4 * 4 + i;
                    wt[i] = (dbase - srel >= 0) ? gs[st] * g0[i] : 0.f;
                }
                const unsigned u0 = (unsigned)f2h(sv[st][0] * wt[0])
                                  | ((unsigned)f2h(sv[st][1] * wt[1]) << 16);
                const unsigned u1 = (unsigned)f2h(sv[st][2] * wt[2])
                                  | ((unsigned)f2h(sv[st][3] * wt[3]) << 16);
                sS[w][l15][st * 8 + q4 * 2]     = u0;
                sS[w][l15][st * 8 + q4 * 2 + 1] = u1;
            }
        }

        // Drain the DS queue before reading back what this wave just wrote:
        // same-wave write->read ordering proved unreliable under contention (R6).
        asm volatile("s_waitcnt lgkmcnt(0)" ::: "memory");

        const u32x4 ua0 = *(const u32x4*)&sS[w][l15][q4 * 4];        // s = q4*8..+7
        const u32x4 ua1 = *(const u32x4*)&sS[w][l15][16 + q4 * 4];   // s = 32+q4*8..+7
        const half8 af0 = __builtin_bit_cast(half8, ua0);
        const half8 af1 = __builtin_bit_cast(half8, ua1);
        #pragma unroll
        for (int ct = 0; ct < 4; ++ct) {
            acc[ct] = __builtin_amdgcn_mfma_f32_16x16x32_f16(af0, vf[ct][0], acc[ct], 0, 0, 0);
            acc[ct] = __builtin_amdgcn_mfma_f32_16x16x32_f16(af1, vf[ct][1], acc[ct], 0, 0, 0);
        }
    }

    // ---- epilogue: reduce 4 partials, GroupNorm, transposed store ----
    #pragma unroll
    for (int ct = 0; ct < 4; ++ct) {
        #pragma unroll
        for (int i = 0; i < 4; ++i)
            sO[w][q4 * 4 + i][ct * 16 + l15] = acc[ct][i];    // D: row=t, col=c
    }
    __syncthreads();
    {
        const int r = tid >> 4, c4 = (tid & 15) * 4;
        f32x4 v = *(const f32x4*)&sO[0][r][c4];
        v += *(const f32x4*)&sO[1][r][c4];
        v += *(const f32x4*)&sO[2][r][c4];
        v += *(const f32x4*)&sO[3][r][c4];
        *(f32x4*)&sO[0][r][c4] = v;
    }
    __syncthreads();
    if (tid < 128) {                             // GN: 16 rows x 8 groups
        const int r = tid >> 3, g = tid & 7;
        float x[8];
        float s = 0.f, ss = 0.f;
        #pragma unroll
        for (int j = 0; j < 8; ++j) {
            x[j] = sO[0][r][g * 8 + j];
            s += x[j]; ss += x[j] * x[j];
        }
        const float mu  = s * 0.125f;
        const float var = ss * 0.125f - mu * mu;
        const float rs  = rsqrtf(var + 1e-6f);
        #pragma unroll
        for (int j = 0; j < 8; ++j) {
            const int c = g * 8 + j;
            sO[0][r][c] = (x[j] - mu) * rs * sGW[c] + sGB[c];
        }
    }
    __syncthreads();
    #pragma unroll
    for (int pass = 0; pass < 4; ++pass) {       // lanes t-contiguous: 64B segments
        const int c = pass * 16 + (tid >> 4);
        const int t = tid & 15;
        out[(size_t)(b * 64 + c) * SEQ + t0 + t] = sO[0][t][c];
    }
}

// ---------------------------------------------------------------------------
extern "C" void kernel_launch(void* const* d_in, const int* in_sizes, int n_in,
                              void* d_out, int out_size, void* d_ws, size_t ws_size,
                              hipStream_t stream)
{
    const float* Xin = (const float*)d_in[0];
    const float* Wq  = (const float*)d_in[1];
    const float* Wk  = (const float*)d_in[2];
    const float* Wv  = (const float*)d_in[3];
    const float* gnw = (const float*)d_in[4];
    const float* gnb = (const float*)d_in[5];

    const size_t NROW = (size_t)2 * SEQ;          // 16384
    unsigned short* Qh = (unsigned short*)d_ws;   // 2 MB each (fp16)
    unsigned short* Kh = Qh + NROW * CH;
    unsigned short* Vt = Kh + NROW * CH;

    qkv_kernel<<<dim3(1024), dim3(192), 0, stream>>>(Xin, Wq, Wk, Wv, Qh, Kh, Vt);
    attn_kernel<<<dim3(1024), dim3(256), 0, stream>>>(Qh, Kh, Vt, gnw, gnb, (float*)d_out);
}